// Round 10
// baseline (83.457 us; speedup 1.0000x reference)
//
#include <hip/hip_runtime.h>

typedef int   int4v   __attribute__((ext_vector_type(4)));
typedef float float4v __attribute__((ext_vector_type(4)));

#define N_DIM 65536

__device__ __forceinline__ int quant8(float v) {
    int q = (int)rintf(v);           // round-half-to-even, matches jnp.round
    q = q > 127 ? 127 : q;
    q = q < -128 ? -128 : q;
    return q;
}

__device__ __forceinline__ int clamp16(int s) {
    s = s > 32767 ? 32767 : s;
    s = s < -32768 ? -32768 : s;
    return s;
}

__device__ __forceinline__ unsigned int qpack(float4v v) {
    int q0 = quant8(v.x * 16.0f);
    int q1 = quant8(v.y * 16.0f);
    int q2 = quant8(v.z * 16.0f);
    int q3 = quant8(v.w * 16.0f);
    return (unsigned int)((q0 & 0xff) | ((q1 & 0xff) << 8) |
                          ((q2 & 0xff) << 16) | ((q3 & 0xff) << 24));
}

// Raw v_exp_f32 (2^x). Args <= 0; deep-negative underflows to 0 on both sides.
__device__ __forceinline__ float fexp2(float a) {
    float r;
    asm("v_exp_f32 %0, %1" : "=v"(r) : "v"(a));
    return r;
}

// Pre-pass: w1/w2 are int-valued float32 in [-16,15]; pack to int8.
__global__ __launch_bounds__(256) void quant_weights(const float* __restrict__ w1,
                                                     const float* __restrict__ w2,
                                                     unsigned char* __restrict__ w1q,
                                                     unsigned char* __restrict__ w2q) {
    int idx = blockIdx.x * 256 + threadIdx.x;   // 32768 threads, 4 elems each
    const float* src;
    unsigned char* dst;
    int off;
    if (idx < 16384) { src = w1; dst = w1q; off = idx * 4; }
    else             { src = w2; dst = w2q; off = (idx - 16384) * 4; }
    float4v f = *reinterpret_cast<const float4v*>(src + off);
    unsigned int dw = (unsigned int)(((int)f.x & 0xff) | (((int)f.y & 0xff) << 8) |
                                     (((int)f.z & 0xff) << 16) | (((int)f.w & 0xff) << 24));
    *reinterpret_cast<unsigned int*>(dst + off) = dw;
}

// Fused kernel: 8 waves/block. Wave w owns rows [w*32, w*32+32); w1 fragments
// persist in registers for the whole kernel; w2 fragments reload per strip
// (L2-hot) to fit the 128-VGPR budget for 2 blocks/CU.
// Block processes 4 strips of 32 columns; x prefetched one strip ahead.
// 3 barriers per strip (max+sum exchange merged via LSE rescale).
__global__ __launch_bounds__(512, 4) void qdq_main(const float* __restrict__ x,
                                                   const unsigned char* __restrict__ w1q,
                                                   const unsigned char* __restrict__ w2q,
                                                   int* __restrict__ out) {
    __shared__ unsigned char xq[8192];   // [32 n][256 d] bytes, swizzled
    __shared__ unsigned char pq[8192];   // [32 n][256 k] bytes, swizzled
    __shared__ int   mb[8][32];          // per-wave column max
    __shared__ float sb[8][32];          // per-wave column partial sum (local max)

    const int tid  = threadIdx.x;
    const int wv   = tid >> 6;      // 0..7
    const int lane = tid & 63;
    const int c    = lane & 15;     // MFMA col-in-tile / A row-in-rowtile
    const int g    = lane >> 4;     // MFMA k-group 0..3

    // x-load / transpose roles: 8 rows x 32 cols (128B segments) per instr
    const int rsub = lane >> 3;     // 0..7
    const int cg   = lane & 7;      // float4 column group
    const int R    = rsub & 3;
    const unsigned int sel1 = (R & 1) ? 0x03070206u : 0x05010400u;
    const unsigned int sel2 = (R & 2) ? 0x07060302u : 0x01000504u;
    const int colsel = (0x3120 >> (R * 4)) & 0xF;   // {0,2,1,3}[R]
    const int n_t = cg * 4 + colsel;                // strip-local col 0..31
    const int qb  = rsub & 4;

    // ---- Persistent GEMM1 A-fragments: rows wv*32 + rt*16 + c, loaded ONCE ----
    int4v a1f[2][4];
    {
        const unsigned char* a1 = w1q + (size_t)(wv * 32 + c) * 256 + g * 16;
        #pragma unroll
        for (int rt = 0; rt < 2; ++rt)
            #pragma unroll
            for (int kk = 0; kk < 4; ++kk)
                a1f[rt][kk] = *reinterpret_cast<const int4v*>(a1 + rt * 4096 + kk * 64);
    }
    const unsigned char* a2 = w2q + (size_t)(wv * 32 + c) * 256 + g * 16;

    const int colstart = blockIdx.x * 128;
    const float* xpb = x + (size_t)(wv * 32 + rsub) * N_DIM + cg * 4;

    // ---- Prologue: strip-0 x loads (wave's rows wv*32 + i*8 + rsub) ----
    float4v raw[4];
    #pragma unroll
    for (int i = 0; i < 4; ++i)
        raw[i] = *reinterpret_cast<const float4v*>(xpb + (size_t)i * (8 * N_DIM) + colstart);

    const float C = 0.0056355275034725134f;   // SCORE_SCALE * log2(e)

    for (int it = 0; it < 4; ++it) {
        const int col0 = colstart + it * 32;

        // ---- 1. Quantize held x; issue next strip's loads ----
        unsigned int Wq[4];
        #pragma unroll
        for (int i = 0; i < 4; ++i) Wq[i] = qpack(raw[i]);
        if (it < 3) {
            #pragma unroll
            for (int i = 0; i < 4; ++i)
                raw[i] = *reinterpret_cast<const float4v*>(
                    xpb + (size_t)i * (8 * N_DIM) + (col0 + 32));
        }

        // ---- 2. 4x4 byte transpose (partners lane^8, lane^16) -> xq ----
        #pragma unroll
        for (int i = 0; i < 4; ++i) {
            unsigned int t = (unsigned int)__shfl_xor((int)Wq[i], 8);
            unsigned int Q = __builtin_amdgcn_perm(t, Wq[i], sel1);
            unsigned int u = (unsigned int)__shfl_xor((int)Q, 16);
            unsigned int F = __builtin_amdgcn_perm(Q, u, sel2);
            const int dbase = wv * 32 + i * 8 + qb;
            *reinterpret_cast<unsigned int*>(
                xq + n_t * 256 + (dbase ^ ((n_t & 15) << 4))) = F;
        }
        __syncthreads();   // T: xq complete

        // ---- 3. GEMM1 by col-tile (only 16 B-frag VGPRs live at once) ----
        unsigned int sc[2][4];
        int im[2];
        #pragma unroll
        for (int t2 = 0; t2 < 2; ++t2) {
            int4v bq[4];
            #pragma unroll
            for (int kk = 0; kk < 4; ++kk)
                bq[kk] = *reinterpret_cast<const int4v*>(
                    xq + (t2 * 16 + c) * 256 + ((kk * 64 + g * 16) ^ (c << 4)));
            int imt = -(1 << 30);
            #pragma unroll
            for (int rt = 0; rt < 2; ++rt) {
                int4v acc = {0, 0, 0, 0};
                #pragma unroll
                for (int kk = 0; kk < 4; ++kk)
                    acc = __builtin_amdgcn_mfma_i32_16x16x64_i8(a1f[rt][kk], bq[kk], acc, 0, 0, 0);
                const int s0 = clamp16(acc[0]), s1 = clamp16(acc[1]);
                const int s2 = clamp16(acc[2]), s3 = clamp16(acc[3]);
                int m01 = s0 > s1 ? s0 : s1, m23 = s2 > s3 ? s2 : s3;
                int m = m01 > m23 ? m01 : m23;
                imt = imt > m ? imt : m;
                sc[t2][2 * rt]     = (unsigned int)((s0 & 0xffff) | (s1 << 16));
                sc[t2][2 * rt + 1] = (unsigned int)((s2 & 0xffff) | (s3 << 16));
            }
            im[t2] = imt;
        }

        // ---- 4. Issue GEMM2 A-fragment loads (L2-hot; consumed after 2 barriers)
        int4v a2f[2][4];
        #pragma unroll
        for (int rt = 0; rt < 2; ++rt)
            #pragma unroll
            for (int kk = 0; kk < 4; ++kk)
                a2f[rt][kk] = *reinterpret_cast<const int4v*>(a2 + rt * 4096 + kk * 64);

        // ---- 5. Wave-level max + local sums; single exchange barrier ----
        {
            int o = __shfl_xor(im[0], 16); im[0] = im[0] > o ? im[0] : o;
            o = __shfl_xor(im[0], 32);     im[0] = im[0] > o ? im[0] : o;
            o = __shfl_xor(im[1], 16);     im[1] = im[1] > o ? im[1] : o;
            o = __shfl_xor(im[1], 32);     im[1] = im[1] > o ? im[1] : o;
        }
        if (g == 0) mb[wv][c] = im[0];
        else if (g == 1) mb[wv][16 + c] = im[1];
        float s0 = 0.0f, s1 = 0.0f;
        #pragma unroll
        for (int i = 0; i < 4; ++i) {
            s0 += fexp2((float)((int)(short)(sc[0][i] & 0xffffu) - im[0]) * C);
            s0 += fexp2((float)(((int)sc[0][i] >> 16) - im[0]) * C);
            s1 += fexp2((float)((int)(short)(sc[1][i] & 0xffffu) - im[1]) * C);
            s1 += fexp2((float)(((int)sc[1][i] >> 16) - im[1]) * C);
        }
        s0 += __shfl_xor(s0, 16); s0 += __shfl_xor(s0, 32);
        s1 += __shfl_xor(s1, 16); s1 += __shfl_xor(s1, 32);
        if (g == 0) sb[wv][c] = s0;
        else if (g == 1) sb[wv][16 + c] = s1;
        __syncthreads();   // MS

        // ---- 6. Combine across waves (LSE rescale) ----
        int gmA = -(1 << 30), gmB = -(1 << 30);
        #pragma unroll
        for (int j = 0; j < 8; ++j) {
            int a = mb[j][c], b = mb[j][16 + c];
            gmA = gmA > a ? gmA : a;
            gmB = gmB > b ? gmB : b;
        }
        float gsA = 0.0f, gsB = 0.0f;
        #pragma unroll
        for (int j = 0; j < 8; ++j) {
            gsA += sb[j][c]      * fexp2((float)(mb[j][c] - gmA) * C);
            gsB += sb[j][16 + c] * fexp2((float)(mb[j][16 + c] - gmB) * C);
        }
        const float qsA = 2048.0f / gsA;
        const float qsB = 2048.0f / gsB;

        // ---- 7. Quantize probs (recompute exp2) -> pq ----
        #pragma unroll
        for (int rt = 0; rt < 2; ++rt) {
            const int koff = wv * 32 + rt * 16 + g * 4;
            {
                const unsigned int w0 = sc[0][2 * rt], w1 = sc[0][2 * rt + 1];
                int q0 = (int)rintf(fexp2((float)((int)(short)(w0 & 0xffffu) - gmA) * C) * qsA);
                int q1 = (int)rintf(fexp2((float)(((int)w0 >> 16) - gmA) * C) * qsA);
                int q2 = (int)rintf(fexp2((float)((int)(short)(w1 & 0xffffu) - gmA) * C) * qsA);
                int q3 = (int)rintf(fexp2((float)(((int)w1 >> 16) - gmA) * C) * qsA);
                q0 = q0 > 127 ? 127 : q0;
                q1 = q1 > 127 ? 127 : q1;
                q2 = q2 > 127 ? 127 : q2;
                q3 = q3 > 127 ? 127 : q3;
                *reinterpret_cast<unsigned int*>(
                    pq + c * 256 + (koff ^ (c << 4))) =
                    (unsigned int)(q0 | (q1 << 8) | (q2 << 16) | (q3 << 24));
            }
            {
                const unsigned int w0 = sc[1][2 * rt], w1 = sc[1][2 * rt + 1];
                int q0 = (int)rintf(fexp2((float)((int)(short)(w0 & 0xffffu) - gmB) * C) * qsB);
                int q1 = (int)rintf(fexp2((float)(((int)w0 >> 16) - gmB) * C) * qsB);
                int q2 = (int)rintf(fexp2((float)((int)(short)(w1 & 0xffffu) - gmB) * C) * qsB);
                int q3 = (int)rintf(fexp2((float)(((int)w1 >> 16) - gmB) * C) * qsB);
                q0 = q0 > 127 ? 127 : q0;
                q1 = q1 > 127 ? 127 : q1;
                q2 = q2 > 127 ? 127 : q2;
                q3 = q3 > 127 ? 127 : q3;
                *reinterpret_cast<unsigned int*>(
                    pq + (16 + c) * 256 + (koff ^ (c << 4))) =
                    (unsigned int)(q0 | (q1 << 8) | (q2 << 16) | (q3 << 24));
            }
        }
        __syncthreads();   // P: pq complete

        // ---- 8. GEMM2 by col-tile; A from per-strip regs; NT stores ----
        #pragma unroll
        for (int t2 = 0; t2 < 2; ++t2) {
            int4v b2[4];
            #pragma unroll
            for (int kk = 0; kk < 4; ++kk)
                b2[kk] = *reinterpret_cast<const int4v*>(
                    pq + (t2 * 16 + c) * 256 + ((kk * 64 + g * 16) ^ (c << 4)));
            #pragma unroll
            for (int rt = 0; rt < 2; ++rt) {
                int4v acc = {0, 0, 0, 0};
                #pragma unroll
                for (int kk = 0; kk < 4; ++kk)
                    acc = __builtin_amdgcn_mfma_i32_16x16x64_i8(a2f[rt][kk], b2[kk], acc, 0, 0, 0);
                #pragma unroll
                for (int r = 0; r < 4; ++r) {
                    const size_t rowoff =
                        (size_t)(wv * 32 + rt * 16 + g * 4 + r) * N_DIM + col0;
                    __builtin_nontemporal_store(clamp16(acc[r]),
                                                &out[rowoff + t2 * 16 + c]);
                }
            }
        }
    }
}

extern "C" void kernel_launch(void* const* d_in, const int* in_sizes, int n_in,
                              void* d_out, int out_size, void* d_ws, size_t ws_size,
                              hipStream_t stream) {
    const float* x  = (const float*)d_in[0];
    const float* w1 = (const float*)d_in[1];
    const float* w2 = (const float*)d_in[2];
    int* out = (int*)d_out;

    unsigned char* w1q = (unsigned char*)d_ws;
    unsigned char* w2q = w1q + 65536;

    quant_weights<<<128, 256, 0, stream>>>(w1, w2, w1q, w2q);
    qdq_main<<<512, 512, 0, stream>>>(x, w1q, w2q, out);
}

// Round 11
// 55.231 us; speedup vs baseline: 1.5111x; 1.5111x over previous
//
#include <hip/hip_runtime.h>

typedef int   int4v   __attribute__((ext_vector_type(4)));
typedef float float4v __attribute__((ext_vector_type(4)));

#define N_DIM 65536

__device__ __forceinline__ int quant8(float v) {
    int q = (int)rintf(v);           // round-half-to-even, matches jnp.round
    q = q > 127 ? 127 : q;
    q = q < -128 ? -128 : q;
    return q;
}

__device__ __forceinline__ int clamp16(int s) {
    s = s > 32767 ? 32767 : s;
    s = s < -32768 ? -32768 : s;
    return s;
}

__device__ __forceinline__ unsigned int qpack(float4v v) {
    int q0 = quant8(v.x * 16.0f);
    int q1 = quant8(v.y * 16.0f);
    int q2 = quant8(v.z * 16.0f);
    int q3 = quant8(v.w * 16.0f);
    return (unsigned int)((q0 & 0xff) | ((q1 & 0xff) << 8) |
                          ((q2 & 0xff) << 16) | ((q3 & 0xff) << 24));
}

// Raw v_exp_f32 (2^x). Args <= 0; deep-negative underflows to 0 on both sides.
__device__ __forceinline__ float fexp2(float a) {
    float r;
    asm("v_exp_f32 %0, %1" : "=v"(r) : "v"(a));
    return r;
}

// Pre-pass: w1/w2 are int-valued float32 in [-16,15]; pack to int8.
__global__ __launch_bounds__(256) void quant_weights(const float* __restrict__ w1,
                                                     const float* __restrict__ w2,
                                                     unsigned char* __restrict__ w1q,
                                                     unsigned char* __restrict__ w2q) {
    int idx = blockIdx.x * 256 + threadIdx.x;   // 32768 threads, 4 elems each
    const float* src;
    unsigned char* dst;
    int off;
    if (idx < 16384) { src = w1; dst = w1q; off = idx * 4; }
    else             { src = w2; dst = w2q; off = (idx - 16384) * 4; }
    float4v f = *reinterpret_cast<const float4v*>(src + off);
    unsigned int dw = (unsigned int)(((int)f.x & 0xff) | (((int)f.y & 0xff) << 8) |
                                     (((int)f.z & 0xff) << 16) | (((int)f.w & 0xff) << 24));
    *reinterpret_cast<unsigned int*>(dst + off) = dw;
}

// Fused kernel: 16 waves/block (1024 thr). Wave w owns rows [w*16, w*16+16)
// of both GEMMs; w1 fragments persist in registers (16 VGPR), w2 fragments
// reload per strip (L2-hot). One block/CU, 4 waves/SIMD.
// Block processes 8 strips of 32 columns; x prefetched one strip ahead.
__global__ __launch_bounds__(1024, 4) void qdq_main(const float* __restrict__ x,
                                                    const unsigned char* __restrict__ w1q,
                                                    const unsigned char* __restrict__ w2q,
                                                    int* __restrict__ out) {
    __shared__ unsigned char xq[8192];   // [32 n][256 d] bytes, swizzled
    __shared__ unsigned char pq[8192];   // [32 n][256 k] bytes, swizzled
    __shared__ int   mb[16][32];         // per-wave column max
    __shared__ float sb[16][32];         // per-wave column partial sum (local max)

    const int tid  = threadIdx.x;
    const int wv   = tid >> 6;      // 0..15
    const int lane = tid & 63;
    const int c    = lane & 15;     // MFMA col-in-tile / A row-in-rowtile
    const int g    = lane >> 4;     // MFMA k-group 0..3

    // x-load / transpose roles: 8 rows x 32 cols (128B segments) per instr
    const int rsub = lane >> 3;     // 0..7
    const int cg   = lane & 7;      // float4 column group
    const int R    = rsub & 3;
    const unsigned int sel1 = (R & 1) ? 0x03070206u : 0x05010400u;
    const unsigned int sel2 = (R & 2) ? 0x07060302u : 0x01000504u;
    const int colsel = (0x3120 >> (R * 4)) & 0xF;   // {0,2,1,3}[R]
    const int n_t = cg * 4 + colsel;                // strip-local col 0..31
    const int qb  = rsub & 4;

    // ---- Persistent GEMM1 A-fragments: row wv*16 + c, loaded ONCE ----
    int4v a1f[4];
    {
        const unsigned char* a1 = w1q + (size_t)(wv * 16 + c) * 256 + g * 16;
        #pragma unroll
        for (int kk = 0; kk < 4; ++kk)
            a1f[kk] = *reinterpret_cast<const int4v*>(a1 + kk * 64);
    }
    const unsigned char* a2 = w2q + (size_t)(wv * 16 + c) * 256 + g * 16;

    const int colstart = blockIdx.x * 256;
    const float* xpb = x + (size_t)(wv * 16 + rsub) * N_DIM + cg * 4;

    // ---- Prologue: strip-0 x loads (wave's rows wv*16 + i*8 + rsub) ----
    float4v raw[2];
    #pragma unroll
    for (int i = 0; i < 2; ++i)
        raw[i] = *reinterpret_cast<const float4v*>(xpb + (size_t)i * (8 * N_DIM) + colstart);

    const float C = 0.0056355275034725134f;   // SCORE_SCALE * log2(e)

    for (int it = 0; it < 8; ++it) {
        const int col0 = colstart + it * 32;

        // ---- 1. Quantize held x; issue next strip's loads ----
        unsigned int Wq[2];
        #pragma unroll
        for (int i = 0; i < 2; ++i) Wq[i] = qpack(raw[i]);
        if (it < 7) {
            #pragma unroll
            for (int i = 0; i < 2; ++i)
                raw[i] = *reinterpret_cast<const float4v*>(
                    xpb + (size_t)i * (8 * N_DIM) + (col0 + 32));
        }

        // ---- 2. 4x4 byte transpose (partners lane^8, lane^16) -> xq ----
        #pragma unroll
        for (int i = 0; i < 2; ++i) {
            unsigned int t = (unsigned int)__shfl_xor((int)Wq[i], 8);
            unsigned int Q = __builtin_amdgcn_perm(t, Wq[i], sel1);
            unsigned int u = (unsigned int)__shfl_xor((int)Q, 16);
            unsigned int F = __builtin_amdgcn_perm(Q, u, sel2);
            const int dbase = wv * 16 + i * 8 + qb;
            *reinterpret_cast<unsigned int*>(
                xq + n_t * 256 + (dbase ^ ((n_t & 15) << 4))) = F;
        }
        __syncthreads();   // T: xq complete

        // ---- 3. GEMM1 by col-tile (A resident; 16 B-frag regs live at once) ----
        unsigned int sc[2][2];
        int im[2];
        #pragma unroll
        for (int t2 = 0; t2 < 2; ++t2) {
            int4v bq[4];
            #pragma unroll
            for (int kk = 0; kk < 4; ++kk)
                bq[kk] = *reinterpret_cast<const int4v*>(
                    xq + (t2 * 16 + c) * 256 + ((kk * 64 + g * 16) ^ (c << 4)));
            int4v acc = {0, 0, 0, 0};
            #pragma unroll
            for (int kk = 0; kk < 4; ++kk)
                acc = __builtin_amdgcn_mfma_i32_16x16x64_i8(a1f[kk], bq[kk], acc, 0, 0, 0);
            const int s0 = clamp16(acc[0]), s1 = clamp16(acc[1]);
            const int s2 = clamp16(acc[2]), s3 = clamp16(acc[3]);
            int m01 = s0 > s1 ? s0 : s1, m23 = s2 > s3 ? s2 : s3;
            im[t2] = m01 > m23 ? m01 : m23;
            sc[t2][0] = (unsigned int)((s0 & 0xffff) | (s1 << 16));
            sc[t2][1] = (unsigned int)((s2 & 0xffff) | (s3 << 16));
        }

        // ---- 4. Wave-level max + local sums; post to LDS ----
        {
            int o = __shfl_xor(im[0], 16); im[0] = im[0] > o ? im[0] : o;
            o = __shfl_xor(im[0], 32);     im[0] = im[0] > o ? im[0] : o;
            o = __shfl_xor(im[1], 16);     im[1] = im[1] > o ? im[1] : o;
            o = __shfl_xor(im[1], 32);     im[1] = im[1] > o ? im[1] : o;
        }
        if (g == 0) mb[wv][c] = im[0];
        else if (g == 1) mb[wv][16 + c] = im[1];
        float s0 = 0.0f, s1 = 0.0f;
        #pragma unroll
        for (int i = 0; i < 2; ++i) {
            s0 += fexp2((float)((int)(short)(sc[0][i] & 0xffffu) - im[0]) * C);
            s0 += fexp2((float)(((int)sc[0][i] >> 16) - im[0]) * C);
            s1 += fexp2((float)((int)(short)(sc[1][i] & 0xffffu) - im[1]) * C);
            s1 += fexp2((float)(((int)sc[1][i] >> 16) - im[1]) * C);
        }
        s0 += __shfl_xor(s0, 16); s0 += __shfl_xor(s0, 32);
        s1 += __shfl_xor(s1, 16); s1 += __shfl_xor(s1, 32);
        if (g == 0) sb[wv][c] = s0;
        else if (g == 1) sb[wv][16 + c] = s1;

        // ---- 5. Issue GEMM2 A-fragment loads (L2-hot, covered by barrier+VALU)
        int4v a2f[4];
        #pragma unroll
        for (int kk = 0; kk < 4; ++kk)
            a2f[kk] = *reinterpret_cast<const int4v*>(a2 + kk * 64);
        __syncthreads();   // MS

        // ---- 6. Combine across 16 waves (LSE rescale) ----
        int gmA = -(1 << 30), gmB = -(1 << 30);
        #pragma unroll
        for (int j = 0; j < 16; ++j) {
            int a = mb[j][c], b = mb[j][16 + c];
            gmA = gmA > a ? gmA : a;
            gmB = gmB > b ? gmB : b;
        }
        float gsA = 0.0f, gsB = 0.0f;
        #pragma unroll
        for (int j = 0; j < 16; ++j) {
            gsA += sb[j][c]      * fexp2((float)(mb[j][c] - gmA) * C);
            gsB += sb[j][16 + c] * fexp2((float)(mb[j][16 + c] - gmB) * C);
        }
        const float qsA = 2048.0f / gsA;
        const float qsB = 2048.0f / gsB;

        // ---- 7. Quantize probs (recompute exp2) -> pq ----
        const int koff = wv * 16 + g * 4;
        {
            const unsigned int w0 = sc[0][0], w1 = sc[0][1];
            int q0 = (int)rintf(fexp2((float)((int)(short)(w0 & 0xffffu) - gmA) * C) * qsA);
            int q1 = (int)rintf(fexp2((float)(((int)w0 >> 16) - gmA) * C) * qsA);
            int q2 = (int)rintf(fexp2((float)((int)(short)(w1 & 0xffffu) - gmA) * C) * qsA);
            int q3 = (int)rintf(fexp2((float)(((int)w1 >> 16) - gmA) * C) * qsA);
            q0 = q0 > 127 ? 127 : q0;
            q1 = q1 > 127 ? 127 : q1;
            q2 = q2 > 127 ? 127 : q2;
            q3 = q3 > 127 ? 127 : q3;
            *reinterpret_cast<unsigned int*>(
                pq + c * 256 + (koff ^ (c << 4))) =
                (unsigned int)(q0 | (q1 << 8) | (q2 << 16) | (q3 << 24));
        }
        {
            const unsigned int w0 = sc[1][0], w1 = sc[1][1];
            int q0 = (int)rintf(fexp2((float)((int)(short)(w0 & 0xffffu) - gmB) * C) * qsB);
            int q1 = (int)rintf(fexp2((float)(((int)w0 >> 16) - gmB) * C) * qsB);
            int q2 = (int)rintf(fexp2((float)((int)(short)(w1 & 0xffffu) - gmB) * C) * qsB);
            int q3 = (int)rintf(fexp2((float)(((int)w1 >> 16) - gmB) * C) * qsB);
            q0 = q0 > 127 ? 127 : q0;
            q1 = q1 > 127 ? 127 : q1;
            q2 = q2 > 127 ? 127 : q2;
            q3 = q3 > 127 ? 127 : q3;
            *reinterpret_cast<unsigned int*>(
                pq + (16 + c) * 256 + (koff ^ (c << 4))) =
                (unsigned int)(q0 | (q1 << 8) | (q2 << 16) | (q3 << 24));
        }
        __syncthreads();   // P: pq complete

        // ---- 8. GEMM2 by col-tile; A from per-strip regs; NT stores ----
        #pragma unroll
        for (int t2 = 0; t2 < 2; ++t2) {
            int4v b2[4];
            #pragma unroll
            for (int kk = 0; kk < 4; ++kk)
                b2[kk] = *reinterpret_cast<const int4v*>(
                    pq + (t2 * 16 + c) * 256 + ((kk * 64 + g * 16) ^ (c << 4)));
            int4v acc = {0, 0, 0, 0};
            #pragma unroll
            for (int kk = 0; kk < 4; ++kk)
                acc = __builtin_amdgcn_mfma_i32_16x16x64_i8(a2f[kk], b2[kk], acc, 0, 0, 0);
            #pragma unroll
            for (int r = 0; r < 4; ++r) {
                const size_t rowoff =
                    (size_t)(wv * 16 + g * 4 + r) * N_DIM + col0;
                __builtin_nontemporal_store(clamp16(acc[r]),
                                            &out[rowoff + t2 * 16 + c]);
            }
        }
    }
}

extern "C" void kernel_launch(void* const* d_in, const int* in_sizes, int n_in,
                              void* d_out, int out_size, void* d_ws, size_t ws_size,
                              hipStream_t stream) {
    const float* x  = (const float*)d_in[0];
    const float* w1 = (const float*)d_in[1];
    const float* w2 = (const float*)d_in[2];
    int* out = (int*)d_out;

    unsigned char* w1q = (unsigned char*)d_ws;
    unsigned char* w2q = w1q + 65536;

    quant_weights<<<128, 256, 0, stream>>>(w1, w2, w1q, w2q);
    qdq_main<<<256, 1024, 0, stream>>>(x, w1q, w2q, out);
}

// Round 12
// 43.962 us; speedup vs baseline: 1.8984x; 1.2563x over previous
//
#include <hip/hip_runtime.h>

typedef int   int4v   __attribute__((ext_vector_type(4)));
typedef float float4v __attribute__((ext_vector_type(4)));

#define N_DIM 65536

__device__ __forceinline__ int quant8(float v) {
    int q = (int)rintf(v);           // round-half-to-even, matches jnp.round
    q = q > 127 ? 127 : q;
    q = q < -128 ? -128 : q;
    return q;
}

__device__ __forceinline__ int clamp16(int s) {
    s = s > 32767 ? 32767 : s;
    s = s < -32768 ? -32768 : s;
    return s;
}

__device__ __forceinline__ unsigned int qpack(float4v v) {
    int q0 = quant8(v.x * 16.0f);
    int q1 = quant8(v.y * 16.0f);
    int q2 = quant8(v.z * 16.0f);
    int q3 = quant8(v.w * 16.0f);
    return (unsigned int)((q0 & 0xff) | ((q1 & 0xff) << 8) |
                          ((q2 & 0xff) << 16) | ((q3 & 0xff) << 24));
}

// Raw v_exp_f32 (2^x). Args <= 0; deep-negative underflows to 0 on both sides.
__device__ __forceinline__ float fexp2(float a) {
    float r;
    asm("v_exp_f32 %0, %1" : "=v"(r) : "v"(a));
    return r;
}

// Pre-pass: w1/w2 are int-valued float32 in [-16,15]; pack to int8.
__global__ __launch_bounds__(256) void quant_weights(const float* __restrict__ w1,
                                                     const float* __restrict__ w2,
                                                     unsigned char* __restrict__ w1q,
                                                     unsigned char* __restrict__ w2q) {
    int idx = blockIdx.x * 256 + threadIdx.x;   // 32768 threads, 4 elems each
    const float* src;
    unsigned char* dst;
    int off;
    if (idx < 16384) { src = w1; dst = w1q; off = idx * 4; }
    else             { src = w2; dst = w2q; off = (idx - 16384) * 4; }
    float4v f = *reinterpret_cast<const float4v*>(src + off);
    unsigned int dw = (unsigned int)(((int)f.x & 0xff) | (((int)f.y & 0xff) << 8) |
                                     (((int)f.z & 0xff) << 16) | (((int)f.w & 0xff) << 24));
    *reinterpret_cast<unsigned int*>(dst + off) = dw;
}

// Fused kernel: 8 waves/block (512 thr). Wave w owns rows [w*32, w*32+32) of
// both GEMMs; w1/w2 fragments register-resident (a2 reloaded per strip from
// L2 under the exchange barrier). Block processes 8 strips of 32 columns;
// x prefetched one strip ahead. 3 barriers/strip (merged max+sum exchange).
__global__ __launch_bounds__(512, 3) void qdq_main(const float* __restrict__ x,
                                                   const unsigned char* __restrict__ w1q,
                                                   const unsigned char* __restrict__ w2q,
                                                   int* __restrict__ out) {
    __shared__ unsigned char xq[8192];   // [32 n][256 d] bytes, swizzled
    __shared__ unsigned char pq[8192];   // [32 n][256 k] bytes, swizzled
    __shared__ int   mb[8][32];          // per-wave column max
    __shared__ float sb[8][32];          // per-wave column partial sum (local max)

    const int tid  = threadIdx.x;
    const int wv   = tid >> 6;      // 0..7
    const int lane = tid & 63;
    const int c    = lane & 15;     // MFMA col-in-tile / A row-in-rowtile
    const int g    = lane >> 4;     // MFMA k-group 0..3

    // x-load / transpose roles: 8 rows x 32 cols (128B segments) per instr
    const int rsub = lane >> 3;     // 0..7
    const int cg   = lane & 7;      // float4 column group
    const int R    = rsub & 3;
    const unsigned int sel1 = (R & 1) ? 0x03070206u : 0x05010400u;
    const unsigned int sel2 = (R & 2) ? 0x07060302u : 0x01000504u;
    const int colsel = (0x3120 >> (R * 4)) & 0xF;   // {0,2,1,3}[R]
    const int n_t = cg * 4 + colsel;                // strip-local col 0..31
    const int qb  = rsub & 4;

    // ---- Persistent GEMM1 A-fragments: rows wv*32 + rt*16 + c, loaded ONCE ----
    int4v a1f[2][4];
    {
        const unsigned char* a1 = w1q + (size_t)(wv * 32 + c) * 256 + g * 16;
        #pragma unroll
        for (int rt = 0; rt < 2; ++rt)
            #pragma unroll
            for (int kk = 0; kk < 4; ++kk)
                a1f[rt][kk] = *reinterpret_cast<const int4v*>(a1 + rt * 4096 + kk * 64);
    }
    const unsigned char* a2 = w2q + (size_t)(wv * 32 + c) * 256 + g * 16;

    const int colstart = blockIdx.x * 256;
    const float* xpb = x + (size_t)(wv * 32 + rsub) * N_DIM + cg * 4;

    // ---- Prologue: strip-0 x loads (wave's rows wv*32 + i*8 + rsub) ----
    float4v raw[4];
    #pragma unroll
    for (int i = 0; i < 4; ++i)
        raw[i] = *reinterpret_cast<const float4v*>(xpb + (size_t)i * (8 * N_DIM) + colstart);

    const float C = 0.0056355275034725134f;   // SCORE_SCALE * log2(e)

    for (int it = 0; it < 8; ++it) {
        const int col0 = colstart + it * 32;

        // ---- 1. Quantize held x; issue next strip's loads ----
        unsigned int Wq[4];
        #pragma unroll
        for (int i = 0; i < 4; ++i) Wq[i] = qpack(raw[i]);
        if (it < 7) {
            #pragma unroll
            for (int i = 0; i < 4; ++i)
                raw[i] = *reinterpret_cast<const float4v*>(
                    xpb + (size_t)i * (8 * N_DIM) + (col0 + 32));
        }

        // ---- 2. 4x4 byte transpose (partners lane^8, lane^16) -> xq ----
        #pragma unroll
        for (int i = 0; i < 4; ++i) {
            unsigned int t = (unsigned int)__shfl_xor((int)Wq[i], 8);
            unsigned int Q = __builtin_amdgcn_perm(t, Wq[i], sel1);
            unsigned int u = (unsigned int)__shfl_xor((int)Q, 16);
            unsigned int F = __builtin_amdgcn_perm(Q, u, sel2);
            const int dbase = wv * 32 + i * 8 + qb;
            *reinterpret_cast<unsigned int*>(
                xq + n_t * 256 + (dbase ^ ((n_t & 15) << 4))) = F;
        }
        __syncthreads();   // T: xq complete

        // ---- 3. B-fragments for GEMM1 (shared by all waves) ----
        int4v bq[2][4];
        #pragma unroll
        for (int t2 = 0; t2 < 2; ++t2)
            #pragma unroll
            for (int kk = 0; kk < 4; ++kk)
                bq[t2][kk] = *reinterpret_cast<const int4v*>(
                    xq + (t2 * 16 + c) * 256 + ((kk * 64 + g * 16) ^ (c << 4)));

        // ---- 4. GEMM1: 2 row-tiles x 2 col-tiles, A resident ----
        unsigned int scA[4], scB[4];
        int imA = -(1 << 30), imB = -(1 << 30);
        #pragma unroll
        for (int rt = 0; rt < 2; ++rt) {
            int4v accA = {0, 0, 0, 0}, accB = {0, 0, 0, 0};
            #pragma unroll
            for (int kk = 0; kk < 4; ++kk) {
                accA = __builtin_amdgcn_mfma_i32_16x16x64_i8(a1f[rt][kk], bq[0][kk], accA, 0, 0, 0);
                accB = __builtin_amdgcn_mfma_i32_16x16x64_i8(a1f[rt][kk], bq[1][kk], accB, 0, 0, 0);
            }
            {
                const int s0 = clamp16(accA[0]), s1 = clamp16(accA[1]);
                const int s2 = clamp16(accA[2]), s3 = clamp16(accA[3]);
                int m01 = s0 > s1 ? s0 : s1, m23 = s2 > s3 ? s2 : s3;
                int m = m01 > m23 ? m01 : m23;
                imA = imA > m ? imA : m;
                scA[2 * rt]     = (unsigned int)((s0 & 0xffff) | (s1 << 16));
                scA[2 * rt + 1] = (unsigned int)((s2 & 0xffff) | (s3 << 16));
            }
            {
                const int s0 = clamp16(accB[0]), s1 = clamp16(accB[1]);
                const int s2 = clamp16(accB[2]), s3 = clamp16(accB[3]);
                int m01 = s0 > s1 ? s0 : s1, m23 = s2 > s3 ? s2 : s3;
                int m = m01 > m23 ? m01 : m23;
                imB = imB > m ? imB : m;
                scB[2 * rt]     = (unsigned int)((s0 & 0xffff) | (s1 << 16));
                scB[2 * rt + 1] = (unsigned int)((s2 & 0xffff) | (s3 << 16));
            }
        }

        // ---- 5. Wave-level max; local-max exp sums (kept in regs); post both ----
        {
            int o = __shfl_xor(imA, 16); imA = imA > o ? imA : o;
            o = __shfl_xor(imA, 32);     imA = imA > o ? imA : o;
            o = __shfl_xor(imB, 16);     imB = imB > o ? imB : o;
            o = __shfl_xor(imB, 32);     imB = imB > o ? imB : o;
        }
        if (g == 0) mb[wv][c] = imA;
        else if (g == 1) mb[wv][16 + c] = imB;
        float eA[8], eB[8];
        float sA = 0.0f, sB = 0.0f;
        #pragma unroll
        for (int i = 0; i < 4; ++i) {
            eA[2 * i]     = fexp2((float)((int)(short)(scA[i] & 0xffffu) - imA) * C);
            eA[2 * i + 1] = fexp2((float)(((int)scA[i] >> 16) - imA) * C);
            sA += eA[2 * i] + eA[2 * i + 1];
            eB[2 * i]     = fexp2((float)((int)(short)(scB[i] & 0xffffu) - imB) * C);
            eB[2 * i + 1] = fexp2((float)(((int)scB[i] >> 16) - imB) * C);
            sB += eB[2 * i] + eB[2 * i + 1];
        }
        sA += __shfl_xor(sA, 16); sA += __shfl_xor(sA, 32);
        sB += __shfl_xor(sB, 16); sB += __shfl_xor(sB, 32);
        if (g == 0) sb[wv][c] = sA;
        else if (g == 1) sb[wv][16 + c] = sB;

        // ---- 6. Issue GEMM2 A-fragment loads (L2-hot; hidden under barrier) ----
        int4v a2f[2][4];
        #pragma unroll
        for (int rt = 0; rt < 2; ++rt)
            #pragma unroll
            for (int kk = 0; kk < 4; ++kk)
                a2f[rt][kk] = *reinterpret_cast<const int4v*>(a2 + rt * 4096 + kk * 64);
        __syncthreads();   // MS

        // ---- 7. Combine across waves (LSE rescale); fold into one scale ----
        int gmA = -(1 << 30), gmB = -(1 << 30);
        #pragma unroll
        for (int j = 0; j < 8; ++j) {
            int a = mb[j][c], b = mb[j][16 + c];
            gmA = gmA > a ? gmA : a;
            gmB = gmB > b ? gmB : b;
        }
        float gsA = 0.0f, gsB = 0.0f;
        #pragma unroll
        for (int j = 0; j < 8; ++j) {
            gsA += sb[j][c]      * fexp2((float)(mb[j][c] - gmA) * C);
            gsB += sb[j][16 + c] * fexp2((float)(mb[j][16 + c] - gmB) * C);
        }
        const float qsA = (2048.0f / gsA) * fexp2((float)(imA - gmA) * C);
        const float qsB = (2048.0f / gsB) * fexp2((float)(imB - gmB) * C);

        // ---- 8. Quantize probs from register exps -> pq ----
        #pragma unroll
        for (int rt = 0; rt < 2; ++rt) {
            const int koff = wv * 32 + rt * 16 + g * 4;
            {
                int q0 = (int)rintf(eA[4 * rt + 0] * qsA);
                int q1 = (int)rintf(eA[4 * rt + 1] * qsA);
                int q2 = (int)rintf(eA[4 * rt + 2] * qsA);
                int q3 = (int)rintf(eA[4 * rt + 3] * qsA);
                q0 = q0 > 127 ? 127 : q0;
                q1 = q1 > 127 ? 127 : q1;
                q2 = q2 > 127 ? 127 : q2;
                q3 = q3 > 127 ? 127 : q3;
                *reinterpret_cast<unsigned int*>(
                    pq + c * 256 + (koff ^ (c << 4))) =
                    (unsigned int)(q0 | (q1 << 8) | (q2 << 16) | (q3 << 24));
            }
            {
                int q0 = (int)rintf(eB[4 * rt + 0] * qsB);
                int q1 = (int)rintf(eB[4 * rt + 1] * qsB);
                int q2 = (int)rintf(eB[4 * rt + 2] * qsB);
                int q3 = (int)rintf(eB[4 * rt + 3] * qsB);
                q0 = q0 > 127 ? 127 : q0;
                q1 = q1 > 127 ? 127 : q1;
                q2 = q2 > 127 ? 127 : q2;
                q3 = q3 > 127 ? 127 : q3;
                *reinterpret_cast<unsigned int*>(
                    pq + (16 + c) * 256 + (koff ^ (c << 4))) =
                    (unsigned int)(q0 | (q1 << 8) | (q2 << 16) | (q3 << 24));
            }
        }
        __syncthreads();   // P: pq complete

        // ---- 9. GEMM2: B from pq, A from per-strip regs; NT stores ----
        int4v b2[2][4];
        #pragma unroll
        for (int t2 = 0; t2 < 2; ++t2)
            #pragma unroll
            for (int kk = 0; kk < 4; ++kk)
                b2[t2][kk] = *reinterpret_cast<const int4v*>(
                    pq + (t2 * 16 + c) * 256 + ((kk * 64 + g * 16) ^ (c << 4)));

        #pragma unroll
        for (int rt = 0; rt < 2; ++rt) {
            int4v accA = {0, 0, 0, 0}, accB = {0, 0, 0, 0};
            #pragma unroll
            for (int kk = 0; kk < 4; ++kk) {
                accA = __builtin_amdgcn_mfma_i32_16x16x64_i8(a2f[rt][kk], b2[0][kk], accA, 0, 0, 0);
                accB = __builtin_amdgcn_mfma_i32_16x16x64_i8(a2f[rt][kk], b2[1][kk], accB, 0, 0, 0);
            }
            #pragma unroll
            for (int r = 0; r < 4; ++r) {
                const size_t rowoff =
                    (size_t)(wv * 32 + rt * 16 + g * 4 + r) * N_DIM + col0;
                __builtin_nontemporal_store(clamp16(accA[r]), &out[rowoff + c]);
                __builtin_nontemporal_store(clamp16(accB[r]), &out[rowoff + 16 + c]);
            }
        }
    }
}

extern "C" void kernel_launch(void* const* d_in, const int* in_sizes, int n_in,
                              void* d_out, int out_size, void* d_ws, size_t ws_size,
                              hipStream_t stream) {
    const float* x  = (const float*)d_in[0];
    const float* w1 = (const float*)d_in[1];
    const float* w2 = (const float*)d_in[2];
    int* out = (int*)d_out;

    unsigned char* w1q = (unsigned char*)d_ws;
    unsigned char* w2q = w1q + 65536;

    quant_weights<<<128, 256, 0, stream>>>(w1, w2, w1q, w2q);
    qdq_main<<<256, 512, 0, stream>>>(x, w1q, w2q, out);
}